// Round 5
// baseline (522.237 us; speedup 1.0000x reference)
//
#include <hip/hip_runtime.h>
#include <hip/hip_bf16.h>

// Problem constants
#define BB 4096
#define NNA 11
#define BN (BB*NNA)      // 45056

// ws float offsets (f32 scratch unless noted)
#define OFF_WEFF   0         // [4][256]
#define OFF_BIASL  1024      // [12][256]
#define OFF_WBIG   4096      // [48][256]
#define OFF_BIAS2  16384     // [256]
#define OFF_WALL   16640     // [48][256]
#define OFF_BIASN  28928     // [11][256]
#define OFF_WG1F   31744     // [48][1152]
#define OFF_BIASG1 87040     // [11][1152]
#define OFF_WG2    99712     // bf16 WT[128][1536] (transposed tail weight), 98304 floats
#define OFF_WQT    198656    // bf16 WQT[64][128], 4096 floats
#define OFF_P2T    202752    // [12][256] per-l bias2 partials
#define OFF_P3T    205824    // [256] bias2@Wfc3_top
#define OFF_WG1FT  206080    // bf16 [1024 cols][64 k]: k<48 = Wg1f^T, k=48+a = biasg1[a]; 16384 floats
#define OFF_MIX    296320    // [4096][242]  attn(121)|A(121)
#define OFF_INTER  1287552   // bf16 region start (float-offset): inter[BN][256], hyp[BN][256]

typedef short bh8 __attribute__((ext_vector_type(8)));   // 8 bf16 (4 VGPRs) MFMA A/B frag
typedef float fx4 __attribute__((ext_vector_type(4)));   // MFMA C/D frag

__device__ __forceinline__ float b2f(__hip_bfloat16 x) { return __bfloat162float(x); }
__device__ __forceinline__ short f2bs(float v) { __hip_bfloat16 h = __float2bfloat16(v); return *(short*)&h; }
__device__ __forceinline__ float s2f(short s) { return __bfloat162float(*(__hip_bfloat16*)&s); }

// ---------- Prologue: weight folding (f32, K-split mini-GEMMs) ----------

// grid 4: C[16][256] = A[16][512] @ W_pos[512][256]
__global__ __launch_bounds__(256) void k_p1(const float* W_in, const float* b_in,
                                            const float* W_pos, const float* b_pos,
                                            float* ws) {
  __shared__ float A[16*512];
  __shared__ float red[4*16*64];
  int t = threadIdx.x, cb = blockIdx.x;
  int ks = t >> 6, c = t & 63, col = cb*64 + c;
  float coef = -logf(10000.f) / 256.f;
  for (int i = t; i < 16*512; i += 256) {
    int row = i >> 9, kk = i & 511;
    float v;
    if (row < 4) v = (kk < 256) ? W_in[row*256 + kk] : 0.f;
    else if (kk < 256) v = b_in[kk];
    else {
      int ii = (kk - 256) >> 1;
      float dv = expf(coef * (float)(2*ii));
      float ang = (float)(row - 4) * dv;
      v = (kk & 1) ? cosf(ang) : sinf(ang);
    }
    A[i] = v;
  }
  __syncthreads();
  float acc[16];
  #pragma unroll
  for (int r = 0; r < 16; ++r) acc[r] = 0.f;
  #pragma unroll 4
  for (int j = 0; j < 128; ++j) {
    int jj = ks*128 + j;
    float b = W_pos[(size_t)jj*256 + col];
    #pragma unroll
    for (int r = 0; r < 16; ++r) acc[r] += A[r*512 + jj] * b;
  }
  #pragma unroll
  for (int r = 0; r < 16; ++r) red[(ks*16 + r)*64 + c] = acc[r];
  __syncthreads();
  for (int i = t; i < 16*64; i += 256) {
    int row = i >> 6, cc = i & 63;
    float s = red[row*64+cc] + red[(16+row)*64+cc] + red[(32+row)*64+cc] + red[(48+row)*64+cc];
    int gcol = cb*64 + cc;
    if (row < 4) ws[OFF_WEFF + row*256 + gcol] = s;
    else         ws[OFF_BIASL + (row-4)*256 + gcol] = s + b_pos[gcol];
  }
}

// grid (4,12)
__global__ __launch_bounds__(256) void k_p2(const float* W_fc2, float* ws) {
  __shared__ float A[5*256];
  __shared__ float red[4*5*64];
  int t = threadIdx.x, cb = blockIdx.x, l = blockIdx.y;
  int ks = t >> 6, c = t & 63, col = cb*64 + c;
  for (int i = t; i < 5*256; i += 256) {
    int row = i >> 8, kk = i & 255;
    A[i] = (row < 4) ? ws[OFF_WEFF + row*256 + kk] : ws[OFF_BIASL + l*256 + kk];
  }
  __syncthreads();
  float acc[5] = {0.f, 0.f, 0.f, 0.f, 0.f};
  #pragma unroll 4
  for (int j = 0; j < 64; ++j) {
    int jj = ks*64 + j;
    float b = W_fc2[(size_t)(l*256 + jj)*256 + col];
    #pragma unroll
    for (int r = 0; r < 5; ++r) acc[r] += A[r*256 + jj] * b;
  }
  #pragma unroll
  for (int r = 0; r < 5; ++r) red[(ks*5 + r)*64 + c] = acc[r];
  __syncthreads();
  for (int i = t; i < 5*64; i += 256) {
    int row = i / 64, cc = i % 64;
    float s = red[row*64+cc] + red[(5+row)*64+cc] + red[(10+row)*64+cc] + red[(15+row)*64+cc];
    int gcol = cb*64 + cc;
    if (row < 4) ws[OFF_WBIG + (l*4 + row)*256 + gcol] = s;
    else         ws[OFF_P2T + l*256 + gcol] = s;
  }
}

// grid 1
__global__ __launch_bounds__(256) void k_p2b(const float* b_fc2, float* ws) {
  int d = threadIdx.x;
  float s = b_fc2[d];
  #pragma unroll
  for (int l = 0; l < 12; ++l) s += ws[OFF_P2T + l*256 + d];
  ws[OFF_BIAS2 + d] = s;
}

// grid (4,7)
__global__ __launch_bounds__(256) void k_p3(const float* W_fc3, float* ws) {
  __shared__ float A[7*256];
  __shared__ float red[4*7*64];
  int t = threadIdx.x, cb = blockIdx.x, rg = blockIdx.y;
  int ks = t >> 6, c = t & 63, col = cb*64 + c;
  for (int i = t; i < 7*256; i += 256) {
    int row = i >> 8, kk = i & 255, gr = rg*7 + row;
    A[i] = (gr < 48) ? ws[OFF_WBIG + gr*256 + kk] : (gr == 48 ? ws[OFF_BIAS2 + kk] : 0.f);
  }
  __syncthreads();
  float acc[7] = {0.f,0.f,0.f,0.f,0.f,0.f,0.f};
  #pragma unroll 4
  for (int j = 0; j < 64; ++j) {
    int jj = ks*64 + j;
    float b = W_fc3[(size_t)jj*256 + col];
    #pragma unroll
    for (int r = 0; r < 7; ++r) acc[r] += A[r*256 + jj] * b;
  }
  #pragma unroll
  for (int r = 0; r < 7; ++r) red[(ks*7 + r)*64 + c] = acc[r];
  __syncthreads();
  for (int i = t; i < 7*64; i += 256) {
    int row = i / 64, cc = i % 64, gr = rg*7 + row;
    float s = red[row*64+cc] + red[(7+row)*64+cc] + red[(14+row)*64+cc] + red[(21+row)*64+cc];
    int gcol = cb*64 + cc;
    if (gr < 48)       ws[OFF_WALL + gr*256 + gcol] = s;
    else if (gr == 48) ws[OFF_P3T + gcol] = s;
  }
}

// grid 11
__global__ __launch_bounds__(256) void k_p3b(const float* W_fc3, const float* b_fc3, float* ws) {
  int d = threadIdx.x, n = blockIdx.x;
  ws[OFF_BIASN + n*256 + d] = ws[OFF_P3T + d] + b_fc3[d] + W_fc3[(size_t)(256+n)*256 + d];
}

// Wg1 column map: [Wm_top|Wm_bot|Wh_top|Wh_bot|Wo_ftraj] (1152 cols)
__device__ __forceinline__ float wg1_elem(int j, int col, const float* W_msg,
                                          const float* W_hyp, const float* W_out) {
  if (col < 256)       return W_msg[j*256 + col];
  else if (col < 512)  return W_msg[(256+j)*256 + (col-256)];
  else if (col < 768)  return W_hyp[j*256 + (col-512)];
  else if (col < 1024) return W_hyp[(256+j)*256 + (col-768)];
  else                 return W_out[(960+j)*128 + (col-1024)];
}

// grid (18,8): rows 0..47 -> Wg1f (+bf16 WG1FT), 48..58 -> biasg1 (+bf16 WG1FT k=48+a)
__global__ __launch_bounds__(256) void k_p4(const float* W_msg, const float* b_msg,
                                            const float* W_hyp, const float* b_hyp,
                                            const float* W_out, float* ws) {
  __shared__ float A[8*256];
  __shared__ float red[4*8*64];
  int t = threadIdx.x, cb = blockIdx.x, rg = blockIdx.y;
  int ks = t >> 6, c = t & 63, col = cb*64 + c;
  for (int i = t; i < 8*256; i += 256) {
    int row = i >> 8, kk = i & 255, gr = rg*8 + row;
    A[i] = (gr < 48) ? ws[OFF_WALL + gr*256 + kk]
         : (gr < 59 ? ws[OFF_BIASN + (gr-48)*256 + kk] : 0.f);
  }
  __syncthreads();
  float acc[8];
  #pragma unroll
  for (int r = 0; r < 8; ++r) acc[r] = 0.f;
  #pragma unroll 4
  for (int j = 0; j < 64; ++j) {
    int jj = ks*64 + j;
    float b = wg1_elem(jj, col, W_msg, W_hyp, W_out);
    #pragma unroll
    for (int r = 0; r < 8; ++r) acc[r] += A[r*256 + jj] * b;
  }
  #pragma unroll
  for (int r = 0; r < 8; ++r) red[(ks*8 + r)*64 + c] = acc[r];
  __syncthreads();
  short* WG1FTs = (short*)(ws + OFF_WG1FT);
  for (int i = t; i < 8*64; i += 256) {
    int row = i >> 6, cc = i & 63, gr = rg*8 + row;
    float s = red[row*64+cc] + red[(8+row)*64+cc] + red[(16+row)*64+cc] + red[(24+row)*64+cc];
    int gcol = cb*64 + cc;
    if (gr < 48) {
      ws[OFF_WG1F + gr*1152 + gcol] = s;
      if (gcol < 1024) WG1FTs[(size_t)gcol*64 + gr] = f2bs(s);
    } else if (gr < 59) {
      if (gcol < 256) s += b_msg[gcol];
      else if (gcol >= 512 && gcol < 768) s += b_hyp[gcol-512];
      ws[OFF_BIASG1 + (gr-48)*1152 + gcol] = s;
      if (gcol < 1024) WG1FTs[(size_t)gcol*64 + gr] = f2bs(s);  // gr = 48+a
    }
  }
}

// grid 1536, block 128: WT[c][r] (bf16, transposed) for the tail MFMA GEMM
__global__ __launch_bounds__(128) void k_p5(const float* W_line, const float* W_out,
                                            float* ws) {
  int c = threadIdx.x, r = blockIdx.x;
  float v;
  if (r < 960)       v = W_out[r*128 + c];
  else if (r < 1216) v = W_out[(r+256)*128 + c];
  else if (r < 1472) {
    int dd = r - 1216;
    float s = 0.f;
    for (int j = 0; j < 64; ++j)
      s += W_line[dd*64 + j] * W_out[(1472+j)*128 + c];
    v = s;
  } else if (r < 1520) {
    v = ws[OFF_WG1F + (r-1472)*1152 + 1024 + c];
  } else v = 0.f;
  short* WTs = (short*)(ws + OFF_WG2);
  WTs[(size_t)c*1536 + r] = f2bs(v);
}

// grid 52: i<8192 -> WQT[n][k] = bf16(W_qz[k][n]); i>=8192 -> zero WG1FT k=59..63
__global__ __launch_bounds__(256) void k_p6(const float* W_qz, float* ws) {
  int i = blockIdx.x*256 + threadIdx.x;
  if (i < 8192) {
    int n = i >> 7, k = i & 127;
    short* WQs = (short*)(ws + OFF_WQT);
    WQs[n*128 + k] = f2bs(W_qz[k*64 + n]);
  } else {
    int j = i - 8192;              // 0..5119
    int col = j / 5, k = 59 + (j % 5);
    short* WG1FTs = (short*)(ws + OFF_WG1FT);
    WG1FTs[(size_t)col*64 + k] = 0;
  }
}

// ---------- Front: ftraj GEMM (K=48) + per-scene corr -> attn/A ----------
__global__ __launch_bounds__(256) void k_front(const float* inputs, float* ws) {
  __shared__ float XT[48*44];
  __shared__ float F[44*260];
  __shared__ float C[4*121];
  int t = threadIdx.x;
  int R0 = blockIdx.x * 44;
  for (int i = t; i < 44*48; i += 256) {
    int r = i / 48, k = i - r*48;
    XT[k*44 + r] = inputs[(size_t)(R0+r)*48 + k];
  }
  __syncthreads();
  {
    int d = t;
    float acc[44];
    #pragma unroll
    for (int r = 0; r < 44; ++r) acc[r] = ws[OFF_BIASN + (r % 11)*256 + d];
    for (int k = 0; k < 48; ++k) {
      float w = ws[OFF_WALL + k*256 + d];
      #pragma unroll
      for (int j = 0; j < 11; ++j) {
        float4 xv = *(const float4*)&XT[k*44 + 4*j];
        acc[4*j+0] += xv.x*w; acc[4*j+1] += xv.y*w;
        acc[4*j+2] += xv.z*w; acc[4*j+3] += xv.w*w;
      }
    }
    #pragma unroll
    for (int r = 0; r < 44; ++r) F[r*260 + d] = acc[r];
  }
  __syncthreads();
  int w = t >> 6, lane = t & 63;
  {
    const float4* F4 = (const float4*)F;
    for (int p = lane; p < 66; p += 64) {
      int n = 0, pp = p;
      while (pp >= 11 - n) { pp -= 11 - n; ++n; }
      int m = n + pp;
      int ra = (w*11 + n) * 65, rb2 = (w*11 + m) * 65;
      float s = 0.f;
      #pragma unroll 4
      for (int j = 0; j < 64; ++j) {
        float4 a = F4[ra + j], b = F4[rb2 + j];
        s += a.x*b.x + a.y*b.y + a.z*b.z + a.w*b.w;
      }
      C[w*121 + n*11 + m] = s;
      C[w*121 + m*11 + n] = s;
    }
  }
  __syncthreads();
  {
    float* Cw = C + w*121;
    float rn[11];
    #pragma unroll
    for (int n = 0; n < 11; ++n) rn[n] = 1.f / sqrtf(Cw[n*11+n]);
    float a = 1e30f;
    for (int n = 0; n < 11; ++n)
      for (int m = 0; m < 11; ++m)
        a = fminf(a, Cw[n*11+m] * rn[n] * rn[m]);
    float thr = (a < 0.4f) ? 0.4f : (((a > 0.4f) && (a < 0.6f)) ? a + 0.1f : a + 0.03f);
    int scene = blockIdx.x*4 + w;
    float* mixb = ws + OFF_MIX + (size_t)scene*242;
    if (lane < 11) {
      int n = lane;
      float mx = -1e30f;
      #pragma unroll
      for (int m = 0; m < 11; ++m) mx = fmaxf(mx, Cw[n*11+m]);
      mx *= (1.f/16.f);
      float e[11], ssum = 0.f;
      #pragma unroll
      for (int m = 0; m < 11; ++m) { e[m] = expf(Cw[n*11+m]*(1.f/16.f) - mx); ssum += e[m]; }
      float inv = 1.f / ssum;
      #pragma unroll
      for (int m = 0; m < 11; ++m) mixb[n*11+m] = e[m]*inv;
      float keep[11], cnt = 0.f;
      #pragma unroll
      for (int m = 0; m < 11; ++m) {
        float q = Cw[n*11+m] * rn[n] * rn[m];
        keep[m] = (q >= thr) ? 1.f : 0.f; cnt += keep[m];
      }
      float sc = 1.f / fmaxf(cnt, 1.f);
      #pragma unroll
      for (int m = 0; m < 11; ++m) mixb[121 + n*11 + m] = keep[m]*sc;
    }
  }
}

// ---------- Mix (MFMA): P = [X48|onehot] @ WG1FT^T (bias folded), attn/A mixing, relu ----------
// grid (1024, 2): 4 scenes (44 rows, pad 48); gy=0 -> inter (attn, Wm), gy=1 -> hyp (A, Wh).
__global__ __launch_bounds__(256) void k_mix(const float* inputs, float* ws,
                                             __hip_bfloat16* outI, __hip_bfloat16* outH) {
  __shared__ short A[48*72];    // X-tile bf16, K=64 (48 X + 11 onehot + pad)
  __shared__ short P[48*520];   // P bf16: cols 0..255 = top, 256..511 = bot
  int t = threadIdx.x;
  int gy = blockIdx.y;
  int S0 = blockIdx.x * 4;
  int R0 = S0 * 11;
  int w = t >> 6, lane = t & 63, quad = lane >> 4, l16 = lane & 15;
  const short* WG1FTs = (const short*)(ws + OFF_WG1FT);

  for (int i = t; i < 384; i += 256) {
    int r = i >> 3, k8 = (i & 7) * 8;
    short tmp[8];
    if (r < 44 && k8 < 48) {
      const float4* sp = (const float4*)(inputs + (size_t)(R0 + r)*48 + k8);
      float4 v0 = sp[0], v1 = sp[1];
      tmp[0]=f2bs(v0.x); tmp[1]=f2bs(v0.y); tmp[2]=f2bs(v0.z); tmp[3]=f2bs(v0.w);
      tmp[4]=f2bs(v1.x); tmp[5]=f2bs(v1.y); tmp[6]=f2bs(v1.z); tmp[7]=f2bs(v1.w);
    } else if (r < 44) {
      int a = r % 11;
      #pragma unroll
      for (int j = 0; j < 8; ++j) tmp[j] = (k8 + j == 48 + a) ? (short)0x3F80 : (short)0;
    } else {
      #pragma unroll
      for (int j = 0; j < 8; ++j) tmp[j] = 0;
    }
    *(bh8*)&A[r*72 + k8] = *(bh8*)tmp;
  }
  __syncthreads();

  fx4 acc[3][8];
  #pragma unroll
  for (int mt = 0; mt < 3; ++mt)
    #pragma unroll
    for (int nt = 0; nt < 8; ++nt) acc[mt][nt] = (fx4){0.f, 0.f, 0.f, 0.f};
  #pragma unroll
  for (int ks = 0; ks < 2; ++ks) {
    int kk = ks*32 + quad*8;
    bh8 a[3], b[8];
    #pragma unroll
    for (int mt = 0; mt < 3; ++mt) a[mt] = *(const bh8*)&A[(mt*16 + l16)*72 + kk];
    #pragma unroll
    for (int nt = 0; nt < 8; ++nt) {
      int col = gy*512 + w*128 + nt*16 + l16;
      b[nt] = *(const bh8*)&WG1FTs[(size_t)col*64 + kk];
    }
    #pragma unroll
    for (int mt = 0; mt < 3; ++mt)
      #pragma unroll
      for (int nt = 0; nt < 8; ++nt)
        acc[mt][nt] = __builtin_amdgcn_mfma_f32_16x16x32_bf16(a[mt], b[nt], acc[mt][nt], 0, 0, 0);
  }
  #pragma unroll
  for (int mt = 0; mt < 3; ++mt)
    #pragma unroll
    for (int nt = 0; nt < 8; ++nt)
      #pragma unroll
      for (int reg = 0; reg < 4; ++reg)
        P[(mt*16 + quad*4 + reg)*520 + w*128 + nt*16 + l16] = f2bs(acc[mt][nt][reg]);
  __syncthreads();

  __hip_bfloat16* dst = gy ? outH : outI;
  int c = t;
  #pragma unroll
  for (int s = 0; s < 4; ++s) {
    float pb[11];
    #pragma unroll
    for (int m = 0; m < 11; ++m) pb[m] = s2f(P[(s*11 + m)*520 + 256 + c]);
    const float* mw = ws + OFF_MIX + (size_t)(S0 + s)*242 + gy*121;   // uniform -> scalar loads
    #pragma unroll
    for (int n = 0; n < 11; ++n) {
      float v = s2f(P[(s*11 + n)*520 + c]);
      #pragma unroll
      for (int m = 0; m < 11; ++m) v += mw[n*11 + m] * pb[m];
      dst[(size_t)(R0 + s*11 + n)*256 + c] = __float2bfloat16(fmaxf(v, 0.f));
    }
  }
}

// ---------- Tail: bf16 MFMA GEMM, M=128 x N=128, K=1536 in 24 chunks of 64 ----------
#define A_OFF 0
#define BT_OFF 9216
#define HS_OFF 0
#define WQ_OFF 17408
__global__ __launch_bounds__(256) void k_g2(const float* past, const float* inputs,
                                            const float* b_out, const float* b_qz,
                                            const __hip_bfloat16* interI, const __hip_bfloat16* hypI,
                                            float* ws, float* out) {
  __shared__ short LDS[26112];   // 52224 B: A[128*72] | BT[128*72] ; epi: hs[128*136]@0, WQ[64*136]@17408
  int t = threadIdx.x;
  int R0 = blockIdx.x * 128;
  int w = t >> 6, lane = t & 63, quad = lane >> 4, l16 = lane & 15;
  const short* WTs = (const short*)(ws + OFF_WG2);
  const short* WQs = (const short*)(ws + OFF_WQT);
  const short* intS = (const short*)interI;
  const short* hypS = (const short*)hypI;

  fx4 acc[8][2];
  #pragma unroll
  for (int mt = 0; mt < 8; ++mt)
    #pragma unroll
    for (int reg = 0; reg < 4; ++reg) {
      int nidx = (R0 + mt*16 + quad*4 + reg) % 11;
      #pragma unroll
      for (int nt = 0; nt < 2; ++nt) {
        int col = w*32 + nt*16 + l16;
        acc[mt][nt][reg] = b_out[col] + ws[OFF_BIASG1 + nidx*1152 + 1024 + col];
      }
    }

  int ar = t >> 1, akh = (t & 1) * 32;   // A-stage: row (0..127), k-half (32 shorts)
  int bn = t >> 1, bkh = (t & 1) * 32;   // B-stage
  for (int ch = 0; ch < 24; ++ch) {
    __syncthreads();
    { // stage A chunk (128 rows x 64 k) bf16
      short tmp[32];
      if (ch < 15) {
        const float4* sp = (const float4*)(past + (size_t)(R0+ar)*960 + ch*64 + akh);
        #pragma unroll
        for (int q = 0; q < 8; ++q) {
          float4 v = sp[q];
          tmp[4*q+0]=f2bs(v.x); tmp[4*q+1]=f2bs(v.y); tmp[4*q+2]=f2bs(v.z); tmp[4*q+3]=f2bs(v.w);
        }
        #pragma unroll
        for (int q = 0; q < 4; ++q)
          *(bh8*)&LDS[A_OFF + ar*72 + akh + q*8] = *(bh8*)&tmp[q*8];
      } else if (ch < 23) {
        const short* s = ((ch < 19) ? intS : hypS) + (size_t)(R0+ar)*256 + ((ch < 19) ? (ch-15) : (ch-19))*64 + akh;
        #pragma unroll
        for (int q = 0; q < 4; ++q)
          *(bh8*)&LDS[A_OFF + ar*72 + akh + q*8] = *(const bh8*)&s[q*8];
      } else {
        #pragma unroll
        for (int q = 0; q < 4; ++q) {
          int k8 = akh + q*8;
          if (k8 < 48) {
            const float4* sp = (const float4*)(inputs + (size_t)(R0+ar)*48 + k8);
            float4 v0 = sp[0], v1 = sp[1];
            tmp[0]=f2bs(v0.x); tmp[1]=f2bs(v0.y); tmp[2]=f2bs(v0.z); tmp[3]=f2bs(v0.w);
            tmp[4]=f2bs(v1.x); tmp[5]=f2bs(v1.y); tmp[6]=f2bs(v1.z); tmp[7]=f2bs(v1.w);
          } else {
            #pragma unroll
            for (int j = 0; j < 8; ++j) tmp[j] = 0;
          }
          *(bh8*)&LDS[A_OFF + ar*72 + k8] = *(bh8*)&tmp[0];
        }
      }
    }
    { // stage BT chunk (128 n x 64 k)
      const short* s = WTs + (size_t)bn*1536 + ch*64 + bkh;
      #pragma unroll
      for (int q = 0; q < 4; ++q)
        *(bh8*)&LDS[BT_OFF + bn*72 + bkh + q*8] = *(const bh8*)&s[q*8];
    }
    __syncthreads();
    #pragma unroll
    for (int ks = 0; ks < 2; ++ks) {
      int kk = ks*32 + quad*8;
      bh8 a[8], b[2];
      #pragma unroll
      for (int mt = 0; mt < 8; ++mt) a[mt] = *(const bh8*)&LDS[A_OFF + (mt*16 + l16)*72 + kk];
      #pragma unroll
      for (int nt = 0; nt < 2; ++nt) b[nt] = *(const bh8*)&LDS[BT_OFF + (w*32 + nt*16 + l16)*72 + kk];
      #pragma unroll
      for (int mt = 0; mt < 8; ++mt)
        #pragma unroll
        for (int nt = 0; nt < 2; ++nt)
          acc[mt][nt] = __builtin_amdgcn_mfma_f32_16x16x32_bf16(a[mt], b[nt], acc[mt][nt], 0, 0, 0);
    }
  }
  __syncthreads();
  #pragma unroll
  for (int mt = 0; mt < 8; ++mt)
    #pragma unroll
    for (int nt = 0; nt < 2; ++nt)
      #pragma unroll
      for (int reg = 0; reg < 4; ++reg)
        LDS[HS_OFF + (mt*16 + quad*4 + reg)*136 + w*32 + nt*16 + l16] = f2bs(fmaxf(acc[mt][nt][reg], 0.f));
  { // stage WQT (64 n x 128 k)
    int n = t >> 2, kh = (t & 3) * 32;
    const short* s = WQs + n*128 + kh;
    #pragma unroll
    for (int q = 0; q < 4; ++q)
      *(bh8*)&LDS[WQ_OFF + n*136 + kh + q*8] = *(const bh8*)&s[q*8];
  }
  __syncthreads();
  fx4 acc2[8];
  {
    float bq = b_qz[w*16 + l16];
    #pragma unroll
    for (int mt = 0; mt < 8; ++mt) { acc2[mt][0]=bq; acc2[mt][1]=bq; acc2[mt][2]=bq; acc2[mt][3]=bq; }
  }
  #pragma unroll
  for (int ks = 0; ks < 4; ++ks) {
    int kk = ks*32 + quad*8;
    bh8 bb = *(const bh8*)&LDS[WQ_OFF + (w*16 + l16)*136 + kk];
    #pragma unroll
    for (int mt = 0; mt < 8; ++mt) {
      bh8 aa = *(const bh8*)&LDS[HS_OFF + (mt*16 + l16)*136 + kk];
      acc2[mt] = __builtin_amdgcn_mfma_f32_16x16x32_bf16(aa, bb, acc2[mt], 0, 0, 0);
    }
  }
  #pragma unroll
  for (int mt = 0; mt < 8; ++mt)
    #pragma unroll
    for (int reg = 0; reg < 4; ++reg)
      out[(size_t)(R0 + mt*16 + quad*4 + reg)*64 + w*16 + l16] = acc2[mt][reg];
}

extern "C" void kernel_launch(void* const* d_in, const int* in_sizes, int n_in,
                              void* d_out, int out_size, void* d_ws, size_t ws_size,
                              hipStream_t stream) {
  const float* inputs = (const float*)d_in[0];
  const float* past   = (const float*)d_in[1];
  const float* W_in   = (const float*)d_in[2];
  const float* b_in   = (const float*)d_in[3];
  const float* W_pos  = (const float*)d_in[4];
  const float* b_pos  = (const float*)d_in[5];
  const float* W_fc2  = (const float*)d_in[6];
  const float* b_fc2  = (const float*)d_in[7];
  const float* W_fc3  = (const float*)d_in[8];
  const float* b_fc3  = (const float*)d_in[9];
  const float* W_msg  = (const float*)d_in[10];
  const float* b_msg  = (const float*)d_in[11];
  const float* W_hyp  = (const float*)d_in[12];
  const float* b_hyp  = (const float*)d_in[13];
  const float* W_line = (const float*)d_in[14];
  const float* W_out  = (const float*)d_in[15];
  const float* b_out  = (const float*)d_in[16];
  const float* W_qz   = (const float*)d_in[17];
  const float* b_qz   = (const float*)d_in[18];
  float* ws = (float*)d_ws;
  __hip_bfloat16* interI = (__hip_bfloat16*)(ws + OFF_INTER);
  __hip_bfloat16* hypI   = interI + (size_t)BN*256;
  float* outp   = (float*)d_out;

  hipLaunchKernelGGL(k_p1,  dim3(4),      dim3(256), 0, stream, W_in, b_in, W_pos, b_pos, ws);
  hipLaunchKernelGGL(k_p2,  dim3(4, 12),  dim3(256), 0, stream, W_fc2, ws);
  hipLaunchKernelGGL(k_p2b, dim3(1),      dim3(256), 0, stream, b_fc2, ws);
  hipLaunchKernelGGL(k_p3,  dim3(4, 7),   dim3(256), 0, stream, W_fc3, ws);
  hipLaunchKernelGGL(k_p3b, dim3(11),     dim3(256), 0, stream, W_fc3, b_fc3, ws);
  hipLaunchKernelGGL(k_p4,  dim3(18, 8),  dim3(256), 0, stream, W_msg, b_msg, W_hyp, b_hyp, W_out, ws);
  hipLaunchKernelGGL(k_p5,  dim3(1536),   dim3(128), 0, stream, W_line, W_out, ws);
  hipLaunchKernelGGL(k_p6,  dim3(52),     dim3(256), 0, stream, W_qz, ws);
  hipLaunchKernelGGL(k_front, dim3(1024), dim3(256), 0, stream, inputs, ws);
  hipLaunchKernelGGL(k_mix, dim3(1024, 2), dim3(256), 0, stream, inputs, ws, interI, hypI);
  hipLaunchKernelGGL(k_g2,  dim3(352),    dim3(256), 0, stream, past, inputs, b_out, b_qz,
                     interI, hypI, ws, outp);
}